// Round 10
// baseline (161.060 us; speedup 1.0000x reference)
//
#include <hip/hip_runtime.h>
#include <stdint.h>

// Problem constants
constexpr int NB = 8;      // batch
constexpr int NS = 2048;   // nodes
constexpr int ND = 256;    // in dim
constexpr int NDO = 256;   // out dim
constexpr int NL = 8;      // labels
constexpr int NE = 32768;  // edges per batch
constexpr int K2 = NL * ND;  // 2048 = concatenated K for the fused GEMM
constexpr int CAP = 32;    // bucket capacity per (b,t,l); binomial max ~14 (12 sigma)

typedef __attribute__((ext_vector_type(8))) short bf16x8;
typedef __attribute__((ext_vector_type(4))) float f32x4;
typedef unsigned int u32;

__device__ __forceinline__ float bf2f(uint32_t u) {
    return __uint_as_float(u << 16);
}
__device__ __forceinline__ uint16_t f2bf(float f) {
    uint32_t x = __float_as_uint(f);
    uint32_t r = (x + 0x7fffu + ((x >> 16) & 1u)) >> 16;
    return (uint16_t)r;
}

// async global->LDS, 16B per lane; lds ptr must be wave-uniform (HW adds lane*16)
__device__ __forceinline__ void gl_lds16(const void* gptr, void* lptr) {
    __builtin_amdgcn_global_load_lds(
        (const __attribute__((address_space(1))) u32*)gptr,
        (__attribute__((address_space(3))) u32*)lptr, 16, 0, 0);
}

// ---- part_kernel: blocks 0..1023 = direct bucket scatter (cursor[(b,t,l)]
//      ends up holding the per-cell count); blocks 1024..1151 = W transpose.
__global__ __launch_bounds__(256) void part_kernel(
    const float* __restrict__ W, ushort* __restrict__ wt2,
    const int* __restrict__ esrc, const int* __restrict__ etgt,
    const int* __restrict__ elab,
    int* __restrict__ cursor, ushort* __restrict__ bucket) {
    int bid = blockIdx.x;
    int tid = threadIdx.x;
    if (bid < 1024) {
        int i = bid * 256 + tid;                     // < NB*NE
        int b = i >> 15;                             // NE = 32768
        int c = (b << 14) + etgt[i] * NL + elab[i];  // (b,t,l) cell
        int p = atomicAdd(&cursor[c], 1);
        if (p < CAP) bucket[(size_t)c * CAP + p] = (ushort)esrc[i];
    } else {
        // W transpose: M[k][o] (k=l*256+d) -> wt2[o][k] bf16, 64x64 tiles
        __shared__ float tile[64][65];               // +1 pad: conflict-free
        int tb = bid - 1024;
        int kt = tb & 31, ot = tb >> 5;
        int k0 = kt * 64, o0 = ot * 64;
        int rr = tid >> 6;                           // 0..3
        int cc = tid & 63;
        for (int r16 = 0; r16 < 16; r16++) {
            int row = r16 * 4 + rr;
            tile[row][cc] = W[(size_t)(k0 + row) * NDO + o0 + cc];
        }
        __syncthreads();
        for (int r16 = 0; r16 < 16; r16++) {
            int orow = r16 * 4 + rr;
            wt2[(size_t)(o0 + orow) * K2 + k0 + cc] = f2bf(tile[cc][orow]);
        }
    }
}

// ---- aggregate: one wave per (b,t); 16384 waves (TLP hides gather latency).
// Pure gather->Z now (bias moved to gemm2 epilogue). Per-label source lists
// from bucket (4 coalesced chunks, static register indexing via shfl).
// Batch pinned to XCD via bid&7 -> x slice (2MB) L2-resident.
__global__ __launch_bounds__(256) void agg_kernel(
    const float* __restrict__ x,
    const int* __restrict__ cursor, const ushort* __restrict__ bucket,
    ushort* __restrict__ Z) {
    int bid = blockIdx.x;                             // 4096 blocks
    int b = bid & 7;                                  // batch == XCD
    int lane = threadIdx.x & 63;
    int t = (bid >> 3) * 4 + (threadIdx.x >> 6);      // 0..2047
    int g = b * NS + t;

    int cv = (lane < 8) ? cursor[(g << 3) + lane] : 0;   // per-label counts

    const ushort* bp = bucket + (size_t)g * (NL * CAP);  // 256 slots
    int my[4];
#pragma unroll
    for (int c = 0; c < 4; c++) my[c] = bp[c * 64 + lane];  // zero-extended

    const float4* x4 = (const float4*)x + (size_t)b * NS * 64;
    ushort* zrow = Z + (size_t)g * K2;

#pragma unroll
    for (int l = 0; l < 8; l++) {
        int n = __shfl(cv, l);
        if (n > CAP) n = CAP;
        float4 a; a.x = a.y = a.z = a.w = 0.f;
        for (int q = 0; q < n; q++) {
            int src = __shfl(my[l >> 1], (l & 1) * CAP + q);
            float4 xv = x4[(size_t)src * 64 + lane];
            a.x += xv.x; a.y += xv.y; a.z += xv.z; a.w += xv.w;
        }
        ushort4 ob;
        ob.x = f2bf(a.x); ob.y = f2bf(a.y); ob.z = f2bf(a.z); ob.w = f2bf(a.w);
        ((ushort4*)(zrow + l * ND))[lane] = ob;
    }
}

// ---- fused GEMM: out[16384x256] = relu(Z @ Wcat + sum_l cnt[t,l]*bias[l])
// 64x128 tile -> 512 blocks (2/CU), BK=128 (32 MFMA per barrier pair, 16 K-steps).
// XOR chunk-swizzle (ch = c ^ (r&7), 16 chunks/row) on BOTH global source
// (gl_lds writes linearly) and ds_read side -> 2 lanes/bank. Bias computed in
// the epilogue from cursor counts (f32). XCD-chunked wgid: batch == bid&7.
__global__ __launch_bounds__(256) void gemm2_kernel(
    const ushort* __restrict__ Z, const ushort* __restrict__ wt2,
    const int* __restrict__ cursor, const float* __restrict__ bias,
    float* __restrict__ out) {
    int wgid = (blockIdx.x & 7) * 64 + (blockIdx.x >> 3);  // bijective over 512
    int m0 = (wgid >> 1) * 64;                 // row tile (256)
    int n0 = (wgid & 1) * 128;                 // col tile (2)

    __shared__ ushort As[64 * 128];            // 16 KB
    __shared__ ushort Bs[128 * 128];           // 32 KB
    __shared__ int cnt_s[64 * 8];              //  2 KB
    __shared__ float bias_s[8 * 128];          //  4 KB

    int tid = threadIdx.x;
    int lane = tid & 63;
    int wave = __builtin_amdgcn_readfirstlane(tid >> 6);
    int wm = wave & 1, wn = wave >> 1;
    int ln = lane & 15, quad = lane >> 4;

    // stage epilogue tables (any later barrier orders these before use)
    {
        int e = tid * 2;
        *(int2*)&cnt_s[e] = *(const int2*)&cursor[(size_t)m0 * 8 + e];
        int f = tid * 4;
        int l = f >> 7, col = f & 127;
        *(float4*)&bias_s[f] = *(const float4*)&bias[l * NDO + n0 + col];
    }

    f32x4 acc[2][4] = {};

    const ushort* Ag = Z + (size_t)m0 * K2;
    const ushort* Bg = wt2 + (size_t)n0 * K2;

    for (int k0 = 0; k0 < K2; k0 += 128) {
        // A: 1024 16B-chunks (64 rows x 16), 4 passes; source chunk pre-swizzled
#pragma unroll
        for (int p = 0; p < 4; p++) {
            int cid = p * 256 + tid;
            int r = cid >> 4, ch = (cid & 15) ^ (r & 7);
            gl_lds16(Ag + (size_t)r * K2 + k0 + ch * 8, &As[(p * 256 + wave * 64) * 8]);
        }
        // B: 2048 chunks (128 rows x 16), 8 passes
#pragma unroll
        for (int p = 0; p < 8; p++) {
            int cid = p * 256 + tid;
            int r = cid >> 4, ch = (cid & 15) ^ (r & 7);
            gl_lds16(Bg + (size_t)r * K2 + k0 + ch * 8, &Bs[(p * 256 + wave * 64) * 8]);
        }
        __syncthreads();

#pragma unroll
        for (int ks = 0; ks < 4; ks++) {
            bf16x8 af[2], bfr[4];
#pragma unroll
            for (int i = 0; i < 2; i++) {
                int row = wm * 32 + i * 16 + ln;
                int ci = (ks * 4 + quad) ^ (row & 7);
                af[i] = *(const bf16x8*)&As[row * 128 + ci * 8];
            }
#pragma unroll
            for (int j = 0; j < 4; j++) {
                int row = wn * 64 + j * 16 + ln;
                int ci = (ks * 4 + quad) ^ (row & 7);
                bfr[j] = *(const bf16x8*)&Bs[row * 128 + ci * 8];
            }
#pragma unroll
            for (int i = 0; i < 2; i++)
#pragma unroll
                for (int j = 0; j < 4; j++)
                    acc[i][j] = __builtin_amdgcn_mfma_f32_16x16x32_bf16(
                        af[i], bfr[j], acc[i][j], 0, 0, 0);
        }
        __syncthreads();
    }

    // epilogue: C/D layout col=lane&15, row=quad*4+r; bias from counts + relu
#pragma unroll
    for (int i = 0; i < 2; i++) {
#pragma unroll
        for (int r = 0; r < 4; r++) {
            int row_l = wm * 32 + i * 16 + quad * 4 + r;
            float cw[8];
#pragma unroll
            for (int l = 0; l < 8; l++) cw[l] = (float)cnt_s[row_l * 8 + l];
#pragma unroll
            for (int j = 0; j < 4; j++) {
                int col_l = wn * 64 + j * 16 + ln;
                float bs = 0.f;
#pragma unroll
                for (int l = 0; l < 8; l++) bs += cw[l] * bias_s[l * 128 + col_l];
                float v = acc[i][j][r] + bs;
                out[(size_t)(m0 + row_l) * NDO + n0 + col_l] = fmaxf(v, 0.f);
            }
        }
    }
}

extern "C" void kernel_launch(void* const* d_in, const int* in_sizes, int n_in,
                              void* d_out, int out_size, void* d_ws, size_t ws_size,
                              hipStream_t stream) {
    const float* x    = (const float*)d_in[0];
    const int*   esrc = (const int*)d_in[1];
    const int*   etgt = (const int*)d_in[2];
    const int*   elab = (const int*)d_in[3];
    const float* W    = (const float*)d_in[4];
    const float* bias = (const float*)d_in[5];
    float* out = (float*)d_out;

    char* ws = (char*)d_ws;
    ushort* wt2    = (ushort*)(ws);                  //   1 MB: Wcat^T bf16 [256][2048]
    int*    cursor = (int*)(ws + 1048576);           // 512 KB: (b,t,l) cursors->counts
    ushort* bucket = (ushort*)(ws + 1572864);        //   8 MB: src ids, (b,t,l)-bucketed
    ushort* Z      = (ushort*)(ws + 10485760);       //  64 MB: aggregated bf16 [16384][2048]

    hipMemsetAsync(cursor, 0, NB * NS * NL * sizeof(int), stream);
    part_kernel<<<1152, 256, 0, stream>>>(W, wt2, esrc, etgt, elab, cursor, bucket);
    agg_kernel<<<4096, 256, 0, stream>>>(x, cursor, bucket, Z);
    gemm2_kernel<<<512, 256, 0, stream>>>(Z, wt2, cursor, bias, out);
}

// Round 11
// 135.808 us; speedup vs baseline: 1.1859x; 1.1859x over previous
//
#include <hip/hip_runtime.h>
#include <stdint.h>

// Problem constants
constexpr int NB = 8;      // batch
constexpr int NS = 2048;   // nodes
constexpr int ND = 256;    // in dim
constexpr int NDO = 256;   // out dim
constexpr int NL = 8;      // labels
constexpr int NE = 32768;  // edges per batch
constexpr int K2 = NL * ND;  // 2048 = concatenated K for the fused GEMM
constexpr int CAP = 32;    // bucket capacity per (b,t,l); binomial max ~14 (12 sigma)

typedef __attribute__((ext_vector_type(8))) short bf16x8;
typedef __attribute__((ext_vector_type(4))) float f32x4;
typedef unsigned int u32;

__device__ __forceinline__ float bf2f(uint32_t u) {
    return __uint_as_float(u << 16);
}
__device__ __forceinline__ uint16_t f2bf(float f) {
    uint32_t x = __float_as_uint(f);
    uint32_t r = (x + 0x7fffu + ((x >> 16) & 1u)) >> 16;
    return (uint16_t)r;
}

// async global->LDS, 16B per lane; lds ptr must be wave-uniform (HW adds lane*16)
__device__ __forceinline__ void gl_lds16(const void* gptr, void* lptr) {
    __builtin_amdgcn_global_load_lds(
        (const __attribute__((address_space(1))) u32*)gptr,
        (__attribute__((address_space(3))) u32*)lptr, 16, 0, 0);
}

// ---- part_kernel: blocks 0..1023 = direct bucket scatter (cursor[(b,t,l)]
//      ends up holding the per-cell count); blocks 1024..1151 = W transpose.
__global__ __launch_bounds__(256) void part_kernel(
    const float* __restrict__ W, ushort* __restrict__ wt2,
    const int* __restrict__ esrc, const int* __restrict__ etgt,
    const int* __restrict__ elab,
    int* __restrict__ cursor, ushort* __restrict__ bucket) {
    int bid = blockIdx.x;
    int tid = threadIdx.x;
    if (bid < 1024) {
        int i = bid * 256 + tid;                     // < NB*NE
        int b = i >> 15;                             // NE = 32768
        int c = (b << 14) + etgt[i] * NL + elab[i];  // (b,t,l) cell
        int p = atomicAdd(&cursor[c], 1);
        if (p < CAP) bucket[(size_t)c * CAP + p] = (ushort)esrc[i];
    } else {
        // W transpose: M[k][o] (k=l*256+d) -> wt2[o][k] bf16, 64x64 tiles
        __shared__ float tile[64][65];               // +1 pad: conflict-free
        int tb = bid - 1024;
        int kt = tb & 31, ot = tb >> 5;
        int k0 = kt * 64, o0 = ot * 64;
        int rr = tid >> 6;                           // 0..3
        int cc = tid & 63;
        for (int r16 = 0; r16 < 16; r16++) {
            int row = r16 * 4 + rr;
            tile[row][cc] = W[(size_t)(k0 + row) * NDO + o0 + cc];
        }
        __syncthreads();
        for (int r16 = 0; r16 < 16; r16++) {
            int orow = r16 * 4 + rr;
            wt2[(size_t)(o0 + orow) * K2 + k0 + cc] = f2bf(tile[cc][orow]);
        }
    }
}

// ---- aggregate: one wave per (b,t); 16384 waves (TLP hides gather latency).
// Pure gather->Z (bias lives in gemm2 epilogue). Per-label source lists from
// bucket (4 coalesced chunks, static register indexing via shfl).
// Batch pinned to XCD via bid&7 -> x slice (2MB) L2-resident.
__global__ __launch_bounds__(256) void agg_kernel(
    const float* __restrict__ x,
    const int* __restrict__ cursor, const ushort* __restrict__ bucket,
    ushort* __restrict__ Z) {
    int bid = blockIdx.x;                             // 4096 blocks
    int b = bid & 7;                                  // batch == XCD
    int lane = threadIdx.x & 63;
    int t = (bid >> 3) * 4 + (threadIdx.x >> 6);      // 0..2047
    int g = b * NS + t;

    int cv = (lane < 8) ? cursor[(g << 3) + lane] : 0;   // per-label counts

    const ushort* bp = bucket + (size_t)g * (NL * CAP);  // 256 slots
    int my[4];
#pragma unroll
    for (int c = 0; c < 4; c++) my[c] = bp[c * 64 + lane];  // zero-extended

    const float4* x4 = (const float4*)x + (size_t)b * NS * 64;
    ushort* zrow = Z + (size_t)g * K2;

#pragma unroll
    for (int l = 0; l < 8; l++) {
        int n = __shfl(cv, l);
        if (n > CAP) n = CAP;
        float4 a; a.x = a.y = a.z = a.w = 0.f;
        for (int q = 0; q < n; q++) {
            int src = __shfl(my[l >> 1], (l & 1) * CAP + q);
            float4 xv = x4[(size_t)src * 64 + lane];
            a.x += xv.x; a.y += xv.y; a.z += xv.z; a.w += xv.w;
        }
        ushort4 ob;
        ob.x = f2bf(a.x); ob.y = f2bf(a.y); ob.z = f2bf(a.z); ob.w = f2bf(a.w);
        ((ushort4*)(zrow + l * ND))[lane] = ob;
    }
}

// ---- fused GEMM: out[16384x256] = relu(Z @ Wcat + sum_l cnt[t,l]*bias[l])
// 64x64 tile -> 1024 blocks = 4 blocks/CU = 16 waves/CU (the grid was the
// occupancy cap at 64x128: 512 blocks = 2/CU = 8 waves, latency-bound).
// BK=64; 4 waves in 2x2, wave tile 32x32 (2x2 MFMA frags). XOR chunk-swizzle
// on BOTH global source (gl_lds writes linearly) and ds_read side. Bias from
// cursor counts in f32 epilogue. XCD map: batch == bid&7 == agg's producer
// XCD, and the 4 n-tiles of an m-tile land on the same XCD (A-panel L2 reuse).
__global__ __launch_bounds__(256, 4) void gemm2_kernel(
    const ushort* __restrict__ Z, const ushort* __restrict__ wt2,
    const int* __restrict__ cursor, const float* __restrict__ bias,
    float* __restrict__ out) {
    int bid = blockIdx.x;
    int wgid = (bid & 7) * 128 + (bid >> 3);   // bijective over 1024
    int mt = wgid >> 2;                        // m-tile 0..255 (batch = mt>>5 = bid&7)
    int n0 = (wgid & 3) * 64;                  // col tile (4)
    int m0 = mt * 64;

    __shared__ ushort As[64 * 64];             //  8 KB
    __shared__ ushort Bs[64 * 64];             //  8 KB
    __shared__ int cnt_s[64 * 8];              //  2 KB
    __shared__ float bias_s[8 * 64];           //  2 KB -> 20 KB total

    int tid = threadIdx.x;
    int lane = tid & 63;
    int wave = __builtin_amdgcn_readfirstlane(tid >> 6);
    int wm = wave & 1, wn = wave >> 1;
    int ln = lane & 15, quad = lane >> 4;

    // stage epilogue tables (ordered before use by the first K-loop barrier)
    {
        int e = tid * 2;
        *(int2*)&cnt_s[e] = *(const int2*)&cursor[(size_t)m0 * 8 + e];
        int l = e >> 6, col = e & 63;
        *(float2*)&bias_s[e] = *(const float2*)&bias[l * NDO + n0 + col];
    }

    f32x4 acc[2][2] = {};

    const ushort* Ag = Z + (size_t)m0 * K2;
    const ushort* Bg = wt2 + (size_t)n0 * K2;

    for (int k0 = 0; k0 < K2; k0 += 64) {
        // A: 512 16B-chunks (64 rows x 8), 2 passes; source chunk pre-swizzled
#pragma unroll
        for (int p = 0; p < 2; p++) {
            int cid = p * 256 + tid;
            int r = cid >> 3, ch = (cid & 7) ^ (r & 7);
            gl_lds16(Ag + (size_t)r * K2 + k0 + ch * 8, &As[(p * 256 + wave * 64) * 8]);
        }
        // B: 512 chunks, 2 passes
#pragma unroll
        for (int p = 0; p < 2; p++) {
            int cid = p * 256 + tid;
            int r = cid >> 3, ch = (cid & 7) ^ (r & 7);
            gl_lds16(Bg + (size_t)r * K2 + k0 + ch * 8, &Bs[(p * 256 + wave * 64) * 8]);
        }
        __syncthreads();

#pragma unroll
        for (int ks = 0; ks < 2; ks++) {
            bf16x8 af[2], bfr[2];
#pragma unroll
            for (int i = 0; i < 2; i++) {
                int row = wm * 32 + i * 16 + ln;
                int ci = (ks * 4 + quad) ^ (row & 7);
                af[i] = *(const bf16x8*)&As[row * 64 + ci * 8];
            }
#pragma unroll
            for (int j = 0; j < 2; j++) {
                int row = wn * 32 + j * 16 + ln;
                int ci = (ks * 4 + quad) ^ (row & 7);
                bfr[j] = *(const bf16x8*)&Bs[row * 64 + ci * 8];
            }
#pragma unroll
            for (int i = 0; i < 2; i++)
#pragma unroll
                for (int j = 0; j < 2; j++)
                    acc[i][j] = __builtin_amdgcn_mfma_f32_16x16x32_bf16(
                        af[i], bfr[j], acc[i][j], 0, 0, 0);
        }
        __syncthreads();
    }

    // epilogue: C/D layout col=lane&15, row=quad*4+r; bias from counts + relu
#pragma unroll
    for (int i = 0; i < 2; i++) {
#pragma unroll
        for (int r = 0; r < 4; r++) {
            int row_l = wm * 32 + i * 16 + quad * 4 + r;
            float cw[8];
#pragma unroll
            for (int l = 0; l < 8; l++) cw[l] = (float)cnt_s[row_l * 8 + l];
#pragma unroll
            for (int j = 0; j < 2; j++) {
                int col_l = wn * 32 + j * 16 + ln;
                float bs = 0.f;
#pragma unroll
                for (int l = 0; l < 8; l++) bs += cw[l] * bias_s[l * 64 + col_l];
                float v = acc[i][j][r] + bs;
                out[(size_t)(m0 + row_l) * NDO + n0 + col_l] = fmaxf(v, 0.f);
            }
        }
    }
}

extern "C" void kernel_launch(void* const* d_in, const int* in_sizes, int n_in,
                              void* d_out, int out_size, void* d_ws, size_t ws_size,
                              hipStream_t stream) {
    const float* x    = (const float*)d_in[0];
    const int*   esrc = (const int*)d_in[1];
    const int*   etgt = (const int*)d_in[2];
    const int*   elab = (const int*)d_in[3];
    const float* W    = (const float*)d_in[4];
    const float* bias = (const float*)d_in[5];
    float* out = (float*)d_out;

    char* ws = (char*)d_ws;
    ushort* wt2    = (ushort*)(ws);                  //   1 MB: Wcat^T bf16 [256][2048]
    int*    cursor = (int*)(ws + 1048576);           // 512 KB: (b,t,l) cursors->counts
    ushort* bucket = (ushort*)(ws + 1572864);        //   8 MB: src ids, (b,t,l)-bucketed
    ushort* Z      = (ushort*)(ws + 10485760);       //  64 MB: aggregated bf16 [16384][2048]

    hipMemsetAsync(cursor, 0, NB * NS * NL * sizeof(int), stream);
    part_kernel<<<1152, 256, 0, stream>>>(W, wt2, esrc, etgt, elab, cursor, bucket);
    agg_kernel<<<4096, 256, 0, stream>>>(x, cursor, bucket, Z);
    gemm2_kernel<<<1024, 256, 0, stream>>>(Z, wt2, cursor, bias, out);
}